// Round 6
// baseline (355.072 us; speedup 1.0000x reference)
//
#include <hip/hip_runtime.h>
#include <cstdint>

// MoE: B=16384 rows, D=2048 feat, E=16 experts, C=64 classes/expert.
// R9: R8 (290us) refuted the B-prefetch theory; budget math says the two
// GEMMs alone can't explain ~205us of stack -- the slack is split-K partial
// round-trips (33MB write + 33MB read), 7 serialized launches, and the
// extra finish pass. Collapse: 3 kernels total.
//  1) convert_w (+ counter zeroing fused; memset launch deleted)
//  2) coarse_fused: R7-proven coarse MFMA + argmax, NOW also fused routing
//     compaction (block-aggregated atomics) + last-done-block schedule
//     build (R8-validated pattern). route_build + eidArr deleted.
//  3) expert_fused: item = 16 rows (~1040 items fills the GPU with NO
//     split-K). Block = 2 waves = 2 K-halves, 4KB LDS reduce (fixed order),
//     then bias+softmax+argmax in-register -> out2/out3 directly.
//     ypartRest (33MB+33MB traffic) and finish_rows deleted.
// f16x3 scheme (R6/R7-proven): a = hi + lo*2^-11, lo prescaled by 2048;
// accH = hi*hi, accC = hi*lo' + lo'*hi; y = accH + accC/2048.
// Fragment convention (R6/R7-validated): A/B frag = 8 contiguous k at
// row/col (lane&15), k-base (lane>>4)*8; D element = (row=(lane>>4)*4+reg,
// col=lane&15).
typedef _Float16 f16;
typedef f16 f16x8 __attribute__((ext_vector_type(8)));
typedef float f32x4 __attribute__((ext_vector_type(4)));
#define MFMA16(a, b, c) __builtin_amdgcn_mfma_f32_16x16x32_f16((a), (b), (c), 0, 0, 0)

static constexpr int B_ = 16384;
static constexpr int D_ = 2048;
static constexpr int E_ = 16;
static constexpr int C_ = 64;
static constexpr float LSC = 2048.0f;   // lo-term scale (2^11)
static constexpr float ILSC = 1.0f / 2048.0f;
static constexpr int TR_X = 16;         // expert item rows (16-row MFMA tile)
static constexpr int MAXITEMS = B_ / TR_X + E_;  // 1040 worst case

// f32 -> (hi f16, lo f16 prescaled by 2048). Bitwise identical to R6-R8.
__device__ __forceinline__ void cvt_hl(const float4 x, const float4 y,
                                       f16x8& h, f16x8& l) {
  const float av[8] = {x.x, x.y, x.z, x.w, y.x, y.y, y.z, y.w};
#pragma unroll
  for (int j = 0; j < 8; ++j) {
    const f16 hh = (f16)av[j];
    h[j] = hh;
    l[j] = (f16)((av[j] - (float)hh) * LSC);
  }
}

// ---- one-shot weight conversion + counter zeroing (memset launch fused) ----
__global__ __launch_bounds__(256) void convert_w(
    const float* __restrict__ cw, const float* __restrict__ ew,
    f16* __restrict__ cwH, f16* __restrict__ cwL,
    f16* __restrict__ ewH, f16* __restrict__ ewL, int* __restrict__ cnt) {
  const int g = blockIdx.x;
  const int tid = threadIdx.x;
  if (g == 0 && tid < 32) cnt[tid] = 0;  // cnt[0..15] + doneCnt + spare
  const float* src;
  f16 *dh, *dl;
  size_t off;
  if (g < 16) {  // cw: 16*2048 elems = 16 blocks * 256 * 8
    off = ((size_t)g * 256 + tid) * 8;
    src = cw; dh = cwH; dl = cwL;
  } else {       // ew: 16*64*2048 elems = 1024 blocks * 256 * 8
    off = ((size_t)(g - 16) * 256 + tid) * 8;
    src = ew; dh = ewH; dl = ewL;
  }
  const float4 v0 = *(const float4*)(src + off);
  const float4 v1 = *(const float4*)(src + off + 4);
  f16x8 h8, l8;
  cvt_hl(v0, v1, h8, l8);
  *(f16x8*)(dh + off) = h8;
  *(f16x8*)(dl + off) = l8;
}

// ---- coarse: f32 feat read ONCE, f16x3 MFMA, fused bias+argmax+ROUTING ----
// 1024 blocks x 512 thr (8 waves). Block owns 16 rows; wave w owns K-range
// [w*256,(w+1)*256) as 8 chunks of 32. A+B prefetched one chunk ahead; no
// K-loop stores. 8 partial C tiles reduced through 8KB LDS. Epilogue:
// bias+argmax -> out0/out1, block-aggregated routing atomics -> rowList,
// last-done block builds the dense (e,tile16) schedule.
__global__ __launch_bounds__(512) void coarse_fused(
    const float* __restrict__ feat, const f16* __restrict__ cwH,
    const f16* __restrict__ cwL, const float* __restrict__ cb,
    float* __restrict__ out0, float* __restrict__ out1,
    int* __restrict__ cnt, int* __restrict__ rowList,
    int* __restrict__ sched, int* __restrict__ nItems,
    int* __restrict__ doneCnt) {
  __shared__ float red[8 * 256];  // [wave][localrow*16 + e]
  __shared__ int lcnt[E_];
  __shared__ int lbase[E_];
  __shared__ int tiles[E_];
  __shared__ int offs[E_];
  __shared__ int isLast;
  const int tid = threadIdx.x;
  const int w = tid >> 6;
  const int lane = tid & 63;
  const int rl = lane & 15;   // feat row within block / expert col
  const int kq = lane >> 4;   // k-quad
  if (tid < E_) lcnt[tid] = 0;
  const int row = blockIdx.x * 16 + rl;
  const int k0 = w * (D_ / 8);

  const float* fr = feat + (size_t)row * D_ + k0 + kq * 8;
  const f16* bhp = cwH + (size_t)rl * D_ + k0 + kq * 8;
  const f16* blp = cwL + (size_t)rl * D_ + k0 + kq * 8;

  f32x4 aH = {0.f, 0.f, 0.f, 0.f};
  f32x4 aC = {0.f, 0.f, 0.f, 0.f};

  // prefetch chunk 0
  float4 v0 = *(const float4*)(fr);
  float4 v1 = *(const float4*)(fr + 4);
  f16x8 bhn = *(const f16x8*)(bhp);
  f16x8 bln = *(const f16x8*)(blp);
#pragma unroll
  for (int ch = 0; ch < 8; ++ch) {
    const float4 c0 = v0, c1 = v1;
    const f16x8 bh = bhn, bl = bln;
    if (ch + 1 < 8) {  // issue next chunk's loads early
      const int ko = (ch + 1) * 32;
      v0 = *(const float4*)(fr + ko);
      v1 = *(const float4*)(fr + ko + 4);
      bhn = *(const f16x8*)(bhp + ko);
      bln = *(const f16x8*)(blp + ko);
    }
    f16x8 h8, l8;
    cvt_hl(c0, c1, h8, l8);
    aH = MFMA16(h8, bh, aH);
    aC = MFMA16(h8, bl, aC);
    aC = MFMA16(l8, bh, aC);
  }
#pragma unroll
  for (int reg = 0; reg < 4; ++reg)
    red[w * 256 + (kq * 4 + reg) * 16 + rl] = aH[reg] + aC[reg] * ILSC;
  __syncthreads();

  int best = -1, lpos = 0, grow = 0;
  if (tid < 256) {
    const int e = tid & 15;
    const int lrow = tid >> 4;
    float val = cb[e];
#pragma unroll
    for (int ww = 0; ww < 8; ++ww) val += red[ww * 256 + tid];
    grow = blockIdx.x * 16 + lrow;
    out0[(size_t)grow * E_ + e] = val;
    // argmax over 16 experts (16-lane group), first-occurrence tie-break
    float av2 = val;
    int ai = e;
#pragma unroll
    for (int off = 8; off; off >>= 1) {
      const float ov = __shfl_xor(av2, off, 16);
      const int oi = __shfl_xor(ai, off, 16);
      if (ov > av2 || (ov == av2 && oi < ai)) { av2 = ov; ai = oi; }
    }
    if (e == 0) {
      out1[grow] = (float)ai;
      best = ai;
      lpos = atomicAdd(&lcnt[ai], 1);
    }
  }
  __syncthreads();
  if (tid < E_) lbase[tid] = atomicAdd(&cnt[tid], lcnt[tid]);
  __syncthreads();
  if (best >= 0) rowList[best * B_ + lbase[best] + lpos] = grow;

  // ---- last-done block builds the (e, tile16) schedule ----
  __syncthreads();
  if (tid == 0) {
    __threadfence();  // publish this block's cnt atomics + rowList stores
    const int d = atomicAdd(doneCnt, 1);
    isLast = (d == (int)gridDim.x - 1) ? 1 : 0;
  }
  __syncthreads();
  if (isLast) {
    if (tid < E_)
      tiles[tid] = (atomicAdd(&cnt[tid], 0) + TR_X - 1) / TR_X;
    __syncthreads();
    if (tid == 0) {
      int acc = 0;
      for (int e2 = 0; e2 < E_; ++e2) { offs[e2] = acc; acc += tiles[e2]; }
      *nItems = acc;
    }
    __syncthreads();
    if (tid < E_) {
      const int o = offs[tid], n = tiles[tid];
      for (int k = 0; k < n; ++k) sched[o + k] = tid | (k << 8);
    }
  }
}

// ---- expert GEMM + finish, fully fused, NO split-K partials ----
// Item = 16 routed rows of one expert (~1040 items). Block = 128 thr =
// 2 waves, wave w computes K-half w (32 chunks of 32); f16x3 MFMA with A
// from f32 feat (L3-warm) converted on the fly, A+B prefetched one chunk
// ahead. K-halves merged via 4KB LDS (fixed order). Epilogue (wave 0):
// bias + softmax + first-occurrence argmax + class-range start -> out2/out3.
__global__ __launch_bounds__(128) void expert_fused(
    const float* __restrict__ feat,
    const f16* __restrict__ ewH, const f16* __restrict__ ewL,
    const float* __restrict__ eb, const int* __restrict__ rowList,
    const int* __restrict__ cnt, const int* __restrict__ sched,
    const int* __restrict__ nItems,
    float* __restrict__ out2, float* __restrict__ out3) {
  __shared__ int rIdx[TR_X];
  __shared__ float yred[TR_X * C_];  // K-half 1 partial, 4 KB
  const int item = blockIdx.x;
  if (item >= *nItems) return;  // uniform per block, before any barrier
  const int s = sched[item];
  const int e = s & 255;
  const int tile = s >> 8;
  const int count = cnt[e];

  const int tid = threadIdx.x;
  if (tid < TR_X) {
    const int slot = tile * TR_X + tid;
    rIdx[tid] = (slot < count) ? rowList[e * B_ + slot] : 0;
  }
  __syncthreads();

  const int lane = tid & 63;
  const int w = tid >> 6;    // K-half
  const int rl = lane & 15;  // A row / B col within 16-tile
  const int kq = lane >> 4;

  const int growA = rIdx[rl];
  constexpr int KR = D_ / 2;        // 1024 per K-half
  constexpr int NCH = KR / 32;      // 32 chunks
  const int k0 = w * KR;

  const float* pa = feat + (size_t)growA * D_ + k0 + kq * 8;
  const size_t eoff = (size_t)e * C_ * D_;
  const f16* pbh[4];
  const f16* pbl[4];
#pragma unroll
  for (int ct = 0; ct < 4; ++ct) {
    const size_t co = eoff + (size_t)(ct * 16 + rl) * D_ + k0 + kq * 8;
    pbh[ct] = ewH + co;
    pbl[ct] = ewL + co;
  }

  f32x4 accH[4], accC[4];
#pragma unroll
  for (int ct = 0; ct < 4; ++ct) {
    accH[ct] = (f32x4){0.f, 0.f, 0.f, 0.f};
    accC[ct] = (f32x4){0.f, 0.f, 0.f, 0.f};
  }

  // prefetch chunk 0: A (f32) + B (f16 h/l)
  float4 na = *(const float4*)(pa);
  float4 nb = *(const float4*)(pa + 4);
  f16x8 bhn[4], bln[4];
#pragma unroll
  for (int ct = 0; ct < 4; ++ct) {
    bhn[ct] = *(const f16x8*)(pbh[ct]);
    bln[ct] = *(const f16x8*)(pbl[ct]);
  }
  for (int ch = 0; ch < NCH; ++ch) {
    const float4 ca = na, cb2 = nb;
    f16x8 bhc[4], blc[4];
#pragma unroll
    for (int ct = 0; ct < 4; ++ct) { bhc[ct] = bhn[ct]; blc[ct] = bln[ct]; }
    if (ch + 1 < NCH) {  // issue next chunk's loads before compute
      const int kn = (ch + 1) * 32;
      na = *(const float4*)(pa + kn);
      nb = *(const float4*)(pa + kn + 4);
#pragma unroll
      for (int ct = 0; ct < 4; ++ct) {
        bhn[ct] = *(const f16x8*)(pbh[ct] + kn);
        bln[ct] = *(const f16x8*)(pbl[ct] + kn);
      }
    }
    f16x8 ah, al;
    cvt_hl(ca, cb2, ah, al);
#pragma unroll
    for (int ct = 0; ct < 4; ++ct) {
      accH[ct] = MFMA16(ah, bhc[ct], accH[ct]);
      accC[ct] = MFMA16(ah, blc[ct], accC[ct]);
      accC[ct] = MFMA16(al, bhc[ct], accC[ct]);
    }
  }

  // merge K-halves: wave 1 deposits, wave 0 reduces (fixed order)
  if (w == 1) {
#pragma unroll
    for (int ct = 0; ct < 4; ++ct)
#pragma unroll
      for (int reg = 0; reg < 4; ++reg)
        yred[(kq * 4 + reg) * C_ + ct * 16 + rl] =
            accH[ct][reg] + accC[ct][reg] * ILSC;
  }
  __syncthreads();
  if (w == 0) {
#pragma unroll
    for (int reg = 0; reg < 4; ++reg) {
      const int lrow = kq * 4 + reg;  // D row = (lane>>4)*4 + reg
      float v[4];
#pragma unroll
      for (int ct = 0; ct < 4; ++ct)
        v[ct] = accH[ct][reg] + accC[ct][reg] * ILSC +
                yred[lrow * C_ + ct * 16 + rl] + eb[e * C_ + ct * 16 + rl];
      // softmax over the row's 64 cols (4 regs x 16 lanes sharing kq)
      float m = fmaxf(fmaxf(v[0], v[1]), fmaxf(v[2], v[3]));
#pragma unroll
      for (int off = 8; off; off >>= 1) m = fmaxf(m, __shfl_xor(m, off, 16));
      float p[4], ssum = 0.f;
#pragma unroll
      for (int ct = 0; ct < 4; ++ct) { p[ct] = __expf(v[ct] - m); ssum += p[ct]; }
#pragma unroll
      for (int off = 8; off; off >>= 1) ssum += __shfl_xor(ssum, off, 16);
      const int slot = tile * TR_X + lrow;
      const int g = rIdx[lrow];
      if (slot < count) {
#pragma unroll
        for (int ct = 0; ct < 4; ++ct)
          out2[(size_t)g * C_ + ct * 16 + rl] = p[ct] / ssum;
      }
      // first-occurrence argmax over the row (col = ct*16 + rl)
      float av = v[0];
      int ai = rl;
#pragma unroll
      for (int ct = 1; ct < 4; ++ct)
        if (v[ct] > av) { av = v[ct]; ai = ct * 16 + rl; }
#pragma unroll
      for (int off = 8; off; off >>= 1) {
        const float ov = __shfl_xor(av, off, 16);
        const int oi = __shfl_xor(ai, off, 16);
        if (ov > av || (ov == av && oi < ai)) { av = ov; ai = oi; }
      }
      if (slot < count && rl == 0) out3[g] = (float)(ai + (e << 6));
    }
  }
}

extern "C" void kernel_launch(void* const* d_in, const int* in_sizes, int n_in,
                              void* d_out, int out_size, void* d_ws,
                              size_t ws_size, hipStream_t stream) {
  const float* feat = (const float*)d_in[0];  // [B, D]
  const float* cw = (const float*)d_in[1];    // [E, D]
  const float* cb = (const float*)d_in[2];    // [E]
  const float* ew = (const float*)d_in[3];    // [E, C, D]
  const float* eb = (const float*)d_in[4];    // [E, C]

  float* out0 = (float*)d_out;           // coarse_output [B, E]
  float* out1 = out0 + (size_t)B_ * E_;  // expert_id [B] (as float)
  float* out2 = out1 + B_;               // local_preds [B, C]
  float* out3 = out2 + (size_t)B_ * C_;  // global_preds [B]

  // ws (~9.3 MB): f16 weights + routing metadata. No partial buffers.
  char* p = (char*)d_ws;
  f16* ewH = (f16*)p;     p += (size_t)E_ * C_ * D_ * 2;  // 4 MB
  f16* ewL = (f16*)p;     p += (size_t)E_ * C_ * D_ * 2;  // 4 MB
  f16* cwH = (f16*)p;     p += (size_t)E_ * D_ * 2;       // 64 KB
  f16* cwL = (f16*)p;     p += (size_t)E_ * D_ * 2;       // 64 KB
  int* rowList = (int*)p; p += (size_t)E_ * B_ * 4;       // 1 MB
  int* cnt = (int*)p;     p += 64 * 4;  // cnt[0..15], doneCnt = cnt[16]
  int* sched = (int*)p;   p += 1056 * 4;
  int* nItems = (int*)p;
  int* doneCnt = cnt + 16;

  // 1) weights -> f16 hi/lo + zero counters (8.5 MB out, ~5 us)
  convert_w<<<16 + 1024, 256, 0, stream>>>(cw, ew, cwH, cwL, ewH, ewL, cnt);
  // 2) coarse MFMA + argmax + routing + schedule (134 MB streamed)
  coarse_fused<<<B_ / 16, 512, 0, stream>>>(feat, cwH, cwL, cb, out0, out1,
                                            cnt, rowList, sched, nItems,
                                            doneCnt);
  // 3) expert MFMA + bias + softmax + argmax, no partials (<=1040 blocks)
  expert_fused<<<MAXITEMS, 128, 0, stream>>>(feat, ewH, ewL, eb, rowList,
                                             cnt, sched, nItems, out2, out3);
}

// Round 7
// 262.466 us; speedup vs baseline: 1.3528x; 1.3528x over previous
//
#include <hip/hip_runtime.h>
#include <cstdint>

// MoE: B=16384 rows, D=2048 feat, E=16 experts, C=64 classes/expert.
// R10: R9's counters finally exposed the coarse kernel: 112us, occ 60%,
// VALU 3.3%, hbm 618GB/s -> stall-bound. Root causes: (1) every A/B load is
// a 16-way scatter (fragment lanes sit on 16 rows, 8KB apart) -> ~16
// transactions/instr; (2) VGPR_Count=32: the compiler serialized the
// "prefetch" (needs ~60+ live regs). Fix on the R7 skeleton (283us best):
//  - weights PACKED into MFMA fragment order (wP[ch][ct][lane][8]) by the
//    convert kernel -> every B load in both GEMMs is ONE coalesced 1KB
//    instr (lane*8 contiguous), L2-hot.
//  - coarse: __launch_bounds__(512,4) (VGPR cap 128) + 2-deep static
//    A-prefetch (pA[2][2], fully unrolled -> compile-time indexed).
//  - expert GEMM: R7 verbatim (TR=128 SK=8; R9's TR=16 replicated B 8x),
//    only B addressing swapped to packed.
// f16x3 scheme (R6/R7-proven): a = hi + lo*2^-11, lo prescaled by 2048;
// accH = hi*hi, accC = hi*lo' + lo'*hi; y = accH + accC/2048.
// Fragment convention (R6/R7-validated): A/B frag = 8 contiguous k at
// row/col (lane&15), k-base (lane>>4)*8; D element = (row=(lane>>4)*4+reg,
// col=lane&15).
typedef _Float16 f16;
typedef f16 f16x8 __attribute__((ext_vector_type(8)));
typedef float f32x4 __attribute__((ext_vector_type(4)));
#define MFMA16(a, b, c) __builtin_amdgcn_mfma_f32_16x16x32_f16((a), (b), (c), 0, 0, 0)

static constexpr int B_ = 16384;
static constexpr int D_ = 2048;
static constexpr int E_ = 16;
static constexpr int C_ = 64;
static constexpr float LSC = 2048.0f;   // lo-term scale (2^11)
static constexpr float ILSC = 1.0f / 2048.0f;
static constexpr int TR_E = 128;        // expert tile rows
static constexpr int SK_E = 8;          // expert split-K
static constexpr int NCHG = D_ / 32;    // 64 global k-chunks
static constexpr int MAXITEMS = (B_ / TR_E) + E_;  // 144 worst case

// f32 -> (hi f16, lo f16 prescaled by 2048). Bitwise identical to R6-R9.
__device__ __forceinline__ void cvt_hl(const float4 x, const float4 y,
                                       f16x8& h, f16x8& l) {
  const float av[8] = {x.x, x.y, x.z, x.w, y.x, y.y, y.z, y.w};
#pragma unroll
  for (int j = 0; j < 8; ++j) {
    const f16 hh = (f16)av[j];
    h[j] = hh;
    l[j] = (f16)((av[j] - (float)hh) * LSC);
  }
}

// ---- weight conversion INTO FRAGMENT-PACKED layout ----
// cwP[ch(64)][lane(64)][8]: lane=(kq<<4)|rl holds cw[rl][ch*32+kq*8 .. +8].
// ewP[e][ch(64)][ct(4)][lane(64)][8]: lane holds ew[e][ct*16+rl][ch*32+kq*8..].
// GEMM-side B load becomes base + lane*8 -> one fully-coalesced 1KB instr.
__global__ __launch_bounds__(256) void convert_pack(
    const float* __restrict__ cw, const float* __restrict__ ew,
    f16* __restrict__ cwPH, f16* __restrict__ cwPL,
    f16* __restrict__ ewPH, f16* __restrict__ ewPL) {
  const int g = blockIdx.x;
  const int tid = threadIdx.x;
  if (g < 16) {  // cw: 64 chunks * 64 lanes = 4096 threads
    const int t = g * 256 + tid;
    const int ch = t >> 6;
    const int lane = t & 63;
    const int rl = lane & 15, kq = lane >> 4;
    const float* src = cw + (size_t)rl * D_ + ch * 32 + kq * 8;
    const float4 v0 = *(const float4*)src;
    const float4 v1 = *(const float4*)(src + 4);
    f16x8 h8, l8;
    cvt_hl(v0, v1, h8, l8);
    *(f16x8*)(cwPH + (size_t)t * 8) = h8;
    *(f16x8*)(cwPL + (size_t)t * 8) = l8;
  } else {       // ew: 16e * 64ch * 4ct * 64lane = 262144 threads
    const int t = (g - 16) * 256 + tid;
    const int lane = t & 63;
    const int ct = (t >> 6) & 3;
    const int ch = (t >> 8) & 63;
    const int e = t >> 14;
    const int rl = lane & 15, kq = lane >> 4;
    const float* src =
        ew + ((size_t)e * C_ + ct * 16 + rl) * D_ + ch * 32 + kq * 8;
    const float4 v0 = *(const float4*)src;
    const float4 v1 = *(const float4*)(src + 4);
    f16x8 h8, l8;
    cvt_hl(v0, v1, h8, l8);
    *(f16x8*)(ewPH + (size_t)t * 8) = h8;
    *(f16x8*)(ewPL + (size_t)t * 8) = l8;
  }
}

// ---- coarse: f32 feat read ONCE, f16x3 MFMA, fused bias+argmax ----
// 1024 blocks x 512 thr. Block owns 16 rows; wave w owns K-range
// [w*256,(w+1)*256) = chunks [w*8, w*8+8). A prefetched 2 deep (static
// pA[2][2], fully unrolled); B from packed cwP (coalesced, L2-hot) 1 deep.
// launch_bounds(512,4): VGPR cap 128 so the prefetch actually lives in regs
// (R6/R9 compiled at VGPR=32 -> serialized loads -> 110us).
__global__ __launch_bounds__(512, 4) void coarse_fused(
    const float* __restrict__ feat, const f16* __restrict__ cwPH,
    const f16* __restrict__ cwPL, const float* __restrict__ cb,
    float* __restrict__ out0, float* __restrict__ out1,
    int* __restrict__ eidArr) {
  __shared__ float red[8 * 256];  // [wave][localrow*16 + e]
  const int tid = threadIdx.x;
  const int w = tid >> 6;
  const int lane = tid & 63;
  const int rl = lane & 15;   // feat row within block / expert col
  const int kq = lane >> 4;   // k-quad
  const int row = blockIdx.x * 16 + rl;

  const float* fr = feat + (size_t)row * D_ + w * 256 + kq * 8;
  const f16* pbh = cwPH + (size_t)(w * 8) * 512 + lane * 8;
  const f16* pbl = cwPL + (size_t)(w * 8) * 512 + lane * 8;

  f32x4 aH = {0.f, 0.f, 0.f, 0.f};
  f32x4 aC = {0.f, 0.f, 0.f, 0.f};

  // prefetch: A 2 chunks deep, B 1 chunk deep (L2-hot)
  float4 pA[2][2];
  pA[0][0] = *(const float4*)(fr);
  pA[0][1] = *(const float4*)(fr + 4);
  pA[1][0] = *(const float4*)(fr + 32);
  pA[1][1] = *(const float4*)(fr + 36);
  f16x8 bh = *(const f16x8*)(pbh);
  f16x8 bl = *(const f16x8*)(pbl);
#pragma unroll
  for (int ch = 0; ch < 8; ++ch) {
    const int cur = ch & 1;  // compile-time after full unroll
    const float4 c0 = pA[cur][0], c1 = pA[cur][1];
    const f16x8 bhc = bh, blc = bl;
    if (ch + 2 < 8) {
      pA[cur][0] = *(const float4*)(fr + (ch + 2) * 32);
      pA[cur][1] = *(const float4*)(fr + (ch + 2) * 32 + 4);
    }
    if (ch + 1 < 8) {
      bh = *(const f16x8*)(pbh + (ch + 1) * 512);
      bl = *(const f16x8*)(pbl + (ch + 1) * 512);
    }
    f16x8 h8, l8;
    cvt_hl(c0, c1, h8, l8);
    aH = MFMA16(h8, bhc, aH);
    aC = MFMA16(h8, blc, aC);
    aC = MFMA16(l8, bhc, aC);
  }
#pragma unroll
  for (int reg = 0; reg < 4; ++reg)
    red[w * 256 + (kq * 4 + reg) * 16 + rl] = aH[reg] + aC[reg] * ILSC;
  __syncthreads();

  if (tid < 256) {
    const int e = tid & 15;
    const int lrow = tid >> 4;
    float val = cb[e];
#pragma unroll
    for (int ww = 0; ww < 8; ++ww) val += red[ww * 256 + tid];
    const int grow = blockIdx.x * 16 + lrow;
    out0[(size_t)grow * E_ + e] = val;
    // argmax over 16 experts (16-lane group), first-occurrence tie-break
    float av2 = val;
    int ai = e;
#pragma unroll
    for (int off = 8; off; off >>= 1) {
      const float ov = __shfl_xor(av2, off, 16);
      const int oi = __shfl_xor(ai, off, 16);
      if (ov > av2 || (ov == av2 && oi < ai)) { av2 = ov; ai = oi; }
    }
    if (e == 0) {
      out1[grow] = (float)ai;
      eidArr[grow] = ai;
    }
  }
}

// ---- routing compaction (R3/R7-proven block-aggregated atomics) ----
__global__ __launch_bounds__(256) void route_build(
    const int* __restrict__ eidArr, int* __restrict__ cnt,
    int* __restrict__ rowList) {
  __shared__ int lcnt[E_];
  __shared__ int lbase[E_];
  const int tid = threadIdx.x;
  if (tid < E_) lcnt[tid] = 0;
  __syncthreads();
  const int row = blockIdx.x * 256 + tid;
  const int best = eidArr[row];
  const int lpos = atomicAdd(&lcnt[best], 1);
  __syncthreads();
  if (tid < E_) lbase[tid] = atomicAdd(&cnt[tid], lcnt[tid]);
  __syncthreads();
  rowList[best * B_ + lbase[best] + lpos] = row;
}

// ---- dense (e, tile) worker list for the expert GEMM ----
__global__ void make_schedule(const int* __restrict__ cnt,
                              int* __restrict__ sched,
                              int* __restrict__ nItems) {
  __shared__ int tiles[E_];
  __shared__ int offs[E_];
  const int t = threadIdx.x;
  if (t < E_) tiles[t] = (cnt[t] + TR_E - 1) / TR_E;
  __syncthreads();
  if (t == 0) {
    int acc = 0;
    for (int e = 0; e < E_; ++e) { offs[e] = acc; acc += tiles[e]; }
    *nItems = acc;
  }
  __syncthreads();
  if (t < E_) {
    const int o = offs[t], n = tiles[t];
    for (int k = 0; k < n; ++k) sched[o + k] = t | (k << 8);
  }
}

// ---- expert GEMM: f16x3 MFMA; A from f32 feat (L3-warm) converted on the
// fly + 1-deep prefetch (R7-proven); B from PACKED ewP -> coalesced 1KB
// loads, L2-hot ----
__global__ __launch_bounds__(256) void expert_gemm(
    const float* __restrict__ feat,
    const f16* __restrict__ ewPH, const f16* __restrict__ ewPL,
    const int* __restrict__ rowList, const int* __restrict__ cnt,
    const int* __restrict__ sched, const int* __restrict__ nItems,
    float* __restrict__ part0, float* __restrict__ partRest) {
  __shared__ int rIdx[TR_E];
  const int b = blockIdx.x;
  const int kz = b % SK_E;
  const int item = b / SK_E;
  if (item >= *nItems) return;  // uniform per block, before any barrier
  const int s = sched[item];
  const int e = s & 255;
  const int tile = s >> 8;
  const int count = cnt[e];

  const int tid = threadIdx.x;
  if (tid < TR_E) {
    const int slot = tile * TR_E + tid;
    rIdx[tid] = (slot < count) ? rowList[e * B_ + slot] : 0;
  }
  __syncthreads();

  const int lane = tid & 63;
  const int w = tid >> 6;
  const int rl = lane & 15;
  const int kq = lane >> 4;

  const int grow0 = rIdx[w * 32 + rl];
  const int grow1 = rIdx[w * 32 + 16 + rl];
  constexpr int KRANGE = D_ / SK_E;  // 256
  constexpr int NCH = KRANGE / 32;   // 8
  const int k0 = kz * KRANGE;

  const float* pa0 = feat + (size_t)grow0 * D_ + k0 + kq * 8;
  const float* pa1 = feat + (size_t)grow1 * D_ + k0 + kq * 8;
  // packed B base: chunk stride 2048 elems (4 ct * 512), ct stride 512
  const f16* pbh = ewPH + ((size_t)e * NCHG + kz * 8) * 2048 + lane * 8;
  const f16* pbl = ewPL + ((size_t)e * NCHG + kz * 8) * 2048 + lane * 8;

  f32x4 accH[2][4], accC[2][4];
#pragma unroll
  for (int s2 = 0; s2 < 2; ++s2)
#pragma unroll
    for (int ct = 0; ct < 4; ++ct) {
      accH[s2][ct] = (f32x4){0.f, 0.f, 0.f, 0.f};
      accC[s2][ct] = (f32x4){0.f, 0.f, 0.f, 0.f};
    }

  // prefetch chunk 0 A (f32)
  float4 n0a = *(const float4*)(pa0);
  float4 n0b = *(const float4*)(pa0 + 4);
  float4 n1a = *(const float4*)(pa1);
  float4 n1b = *(const float4*)(pa1 + 4);
#pragma unroll
  for (int ch = 0; ch < NCH; ++ch) {
    const float4 c0a = n0a, c0b = n0b, c1a = n1a, c1b = n1b;
    if (ch + 1 < NCH) {
      const int kn = (ch + 1) * 32;
      n0a = *(const float4*)(pa0 + kn);
      n0b = *(const float4*)(pa0 + kn + 4);
      n1a = *(const float4*)(pa1 + kn);
      n1b = *(const float4*)(pa1 + kn + 4);
    }
    f16x8 a0h, a0l, a1h, a1l;
    cvt_hl(c0a, c0b, a0h, a0l);
    cvt_hl(c1a, c1b, a1h, a1l);
#pragma unroll
    for (int ct = 0; ct < 4; ++ct) {
      const f16x8 bh = *(const f16x8*)(pbh + ch * 2048 + ct * 512);
      const f16x8 bl = *(const f16x8*)(pbl + ch * 2048 + ct * 512);
      accH[0][ct] = MFMA16(a0h, bh, accH[0][ct]);
      accC[0][ct] = MFMA16(a0h, bl, accC[0][ct]);
      accC[0][ct] = MFMA16(a0l, bh, accC[0][ct]);
      accH[1][ct] = MFMA16(a1h, bh, accH[1][ct]);
      accC[1][ct] = MFMA16(a1h, bl, accC[1][ct]);
      accC[1][ct] = MFMA16(a1l, bh, accC[1][ct]);
    }
  }

  float* pk = kz ? (partRest + (size_t)(kz - 1) * B_ * C_) : part0;
#pragma unroll
  for (int s2 = 0; s2 < 2; ++s2)
#pragma unroll
    for (int reg = 0; reg < 4; ++reg) {
      const int rloc = w * 32 + s2 * 16 + kq * 4 + reg;
      const int slot = tile * TR_E + rloc;
      if (slot < count) {
        const int g = rIdx[rloc];
#pragma unroll
        for (int ct = 0; ct < 4; ++ct)
          pk[(size_t)g * C_ + ct * 16 + rl] =
              accH[s2][ct][reg] + accC[s2][ct][reg] * ILSC;
      }
    }
}

// ---- wave-per-row: reduce y partials (fixed order), bias, softmax, argmax ----
template <int SK>
__global__ __launch_bounds__(256) void finish_rows(
    const float* __restrict__ ypart0, const float* __restrict__ ypartRest,
    const float* __restrict__ eb, const int* __restrict__ eidArr,
    float* __restrict__ out2, float* __restrict__ out3) {
  const int lane = threadIdx.x & 63;
  const int row = (blockIdx.x * 256 + threadIdx.x) >> 6;
  const int eid = eidArr[row];

  float v = eb[eid * C_ + lane];
  v += ypart0[(size_t)row * C_ + lane];
#pragma unroll
  for (int kz = 1; kz < SK; ++kz)
    v += ypartRest[((size_t)(kz - 1) * B_ + row) * C_ + lane];

  float m = v;
#pragma unroll
  for (int off = 32; off; off >>= 1) m = fmaxf(m, __shfl_xor(m, off, 64));
  const float p = __expf(v - m);
  float s = p;
#pragma unroll
  for (int off = 32; off; off >>= 1) s += __shfl_xor(s, off, 64);
  out2[(size_t)row * C_ + lane] = p / s;  // ypart0 aliases out2; read done

  float av = v;
  int ai = lane;
#pragma unroll
  for (int off = 32; off; off >>= 1) {
    const float ov = __shfl_xor(av, off, 64);
    const int oi = __shfl_xor(ai, off, 64);
    if (ov > av || (ov == av && oi < ai)) { av = ov; ai = oi; }
  }
  if (lane == 0) out3[row] = (float)(ai + (eid << 6));
}

extern "C" void kernel_launch(void* const* d_in, const int* in_sizes, int n_in,
                              void* d_out, int out_size, void* d_ws,
                              size_t ws_size, hipStream_t stream) {
  const float* feat = (const float*)d_in[0];  // [B, D]
  const float* cw = (const float*)d_in[1];    // [E, D]
  const float* cb = (const float*)d_in[2];    // [E]
  const float* ew = (const float*)d_in[3];    // [E, C, D]
  const float* eb = (const float*)d_in[4];    // [E, C]

  float* out0 = (float*)d_out;           // coarse_output [B, E]
  float* out1 = out0 + (size_t)B_ * E_;  // expert_id [B] (as float)
  float* out2 = out1 + B_;               // local_preds [B, C]
  float* out3 = out2 + (size_t)B_ * C_;  // global_preds [B]

  // ws (~40 MB): packed f16 weights + kz>=1 y-partials + routing metadata.
  char* p = (char*)d_ws;
  f16* ewPH = (f16*)p;    p += (size_t)E_ * C_ * D_ * 2;  // 4 MB
  f16* ewPL = (f16*)p;    p += (size_t)E_ * C_ * D_ * 2;  // 4 MB
  f16* cwPH = (f16*)p;    p += (size_t)E_ * D_ * 2;       // 64 KB
  f16* cwPL = (f16*)p;    p += (size_t)E_ * D_ * 2;       // 64 KB
  float* ypartRest = (float*)p; p += (size_t)(SK_E - 1) * B_ * C_ * 4;  // 29.4 MB
  int* rowList = (int*)p; p += (size_t)E_ * B_ * 4;       // 1 MB
  int* cnt = (int*)p;     p += 64 * 4;
  int* eidArr = (int*)p;  p += (size_t)B_ * 4;
  int* sched = (int*)p;   p += 512 * 4;
  int* nItems = (int*)p;

  hipMemsetAsync(cnt, 0, E_ * sizeof(int), stream);

  // 1) weights -> fragment-packed f16 hi/lo (8.6 MB out)
  convert_pack<<<16 + 1024, 256, 0, stream>>>(cw, ew, cwPH, cwPL, ewPH, ewPL);
  // 2) coarse MFMA + argmax (134 MB streamed; 1024 blocks)
  coarse_fused<<<B_ / 16, 512, 0, stream>>>(feat, cwPH, cwPL, cb, out0, out1,
                                            eidArr);
  // 3) routing compaction + dense worker list
  route_build<<<B_ / 256, 256, 0, stream>>>(eidArr, cnt, rowList);
  make_schedule<<<1, 64, 0, stream>>>(cnt, sched, nItems);
  // 4) expert MFMA GEMM (<=144 items * SK 8 = 1152 blocks)
  expert_gemm<<<MAXITEMS * SK_E, 256, 0, stream>>>(
      feat, ewPH, ewPL, rowList, cnt, sched, nItems, out2, ypartRest);
  // 5) softmax + argmax + class-range start
  finish_rows<SK_E><<<(B_ * 64) / 256, 256, 0, stream>>>(out2, ypartRest, eb,
                                                         eidArr, out2, out3);
}